// Round 4
// baseline (112.020 us; speedup 1.0000x reference)
//
#include <hip/hip_runtime.h>
#include <stdint.h>

#define NQ 14
#define STATE 16384
#define BATCH 512
#define GRID 256                  // persistent: block b pipelines rows b and b+256
#define THREADS 512
#define PER 32
#define STRIDE 132                 // 128 + 4-word pad: bank-rotates rows, keeps 16B align
#define LDS_WORDS (128 * STRIDE)  // 16896 words = 67584 B (one buffer, reused per row)
#define SCALE 6.103515625e-05f    // 2^-14: both FWHT norms folded into the rotation trig

typedef float v2f __attribute__((ext_vector_type(2)));  // (re, im) or (even, odd) pair
typedef float v4f __attribute__((ext_vector_type(4)));  // native vec4: nontemporal-capable

// Raw workgroup barrier with LDS-ordering ONLY (lgkmcnt). __syncthreads() would
// emit s_waitcnt vmcnt(0) before s_barrier, draining the cross-row global-load
// prefetch — the whole point of the 2-row pipeline is that row-B loads stay in
// flight across row-A's barriers. "memory" clobber orders all LDS (memory) ops
// across the asm; VALU may cross, which is harmless.
#define BAR() asm volatile("s_waitcnt lgkmcnt(0)\n\ts_barrier" ::: "memory")

__device__ __forceinline__ int adr(int row, int col) { return row * STRIDE + col; }

// bf16-pair packing: one b32 word = complex element (re lo16, im hi16).
__device__ __forceinline__ uint32_t pkc(v2f v) {
    uint32_t w;
    asm("v_cvt_pk_bf16_f32 %0, %1, %2" : "=v"(w) : "v"(v[0]), "v"(v[1]));
    return w;
}
__device__ __forceinline__ v2f upkc(uint32_t w) {
    v2f v;
    v[0] = __uint_as_float(w << 16);
    v[1] = __uint_as_float(w & 0xFFFF0000u);
    return v;
}

// Packed complex FWHT over register bits m=1..MAXM (transform 1).
template <int MAXM>
__device__ __forceinline__ void fwht_pk(v2f (&x)[PER]) {
#pragma unroll
    for (int m = 1; m <= MAXM; m <<= 1) {
#pragma unroll
        for (int r = 0; r < PER; ++r) {
            if (!(r & m)) {
                v2f a = x[r], b = x[r | m];
                x[r] = a + b;
                x[r | m] = a - b;
            }
        }
    }
}
// Transform-2 helpers: 16 v2f regs hold 32 reals paired along LDS-adjacent bit r0.
template <int MAXM>
__device__ __forceinline__ void fwht_q(v2f (&x)[16]) {
#pragma unroll
    for (int m = 1; m <= MAXM; m <<= 1) {
#pragma unroll
        for (int u = 0; u < 16; ++u) {
            if (!(u & m)) {
                v2f a = x[u], c = x[u | m];
                x[u] = a + c;
                x[u | m] = a - c;
            }
        }
    }
}
// hbf: butterfly over the pair axis itself (bit r0): (lo,hi)->(lo+hi,lo-hi).
__device__ __forceinline__ void hbf(v2f (&x)[16]) {
#pragma unroll
    for (int u = 0; u < 16; ++u) {
        float a = x[u][0], c = x[u][1];
        x[u][0] = a + c;
        x[u][1] = a - c;
    }
}

// Word-address maps (word index = complex element in t1, real f32 in t2):
// L0: s = (r>>2)*2048 + t*4 + (r&3)   reg bits s{0,1,11,12,13}; rows cross-wave
// L1: s = (t>>2)*128 + r*4 + (t&3)    reg bits s{2..6};  rows [16w,16w+16): wave-local
// L2: s = (t>>6)*2048 + (r&15)*128 + (r>>4)*64 + ((t>>2)&15)*4 + (t&3)
//     reg bits s{6..10}; rows [16w,16w+16): wave-local
// LDS address of s: adr(s>>7, s&127).  All patterns <=2 lanes/bank (free).

__device__ __forceinline__ void load_row(const float* __restrict__ phr,
                                         const float* __restrict__ phim,
                                         int row, int t, v2f (&x)[PER]) {
    const float* pr = phr + (size_t)row * STATE;
    const float* pi = phim + (size_t)row * STATE;
#pragma unroll
    for (int i = 0; i < 8; ++i) {
        float4 a = *(const float4*)(pr + i * 2048 + t * 4);
        float4 c = *(const float4*)(pi + i * 2048 + t * 4);
        x[4 * i]     = v2f{a.x, c.x};
        x[4 * i + 1] = v2f{a.y, c.y};
        x[4 * i + 2] = v2f{a.z, c.z};
        x[4 * i + 3] = v2f{a.w, c.w};
    }
}

// One full row: t1 (complex) -> rotation -> t2 (real) -> store. Identical math
// to the verified single-row kernel; __syncthreads replaced by raw BAR().
__device__ __forceinline__ void process_row(v2f (&x)[PER], const float (&w)[NQ],
                                            float* lds, uint32_t* ldsw, int t,
                                            float* o, long long ob,
                                            long long out_limit) {
    // ---- transform 1: L0 bits {0,1,11,12,13} (complex fp32, packed math) ----
    fwht_pk<16>(x);

    // XCHG1 (L0 -> L1): ONE pass, complex packed as bf16-pair words. 1 barrier.
    {
#pragma unroll
        for (int i = 0; i < 8; ++i) {
            uint4 v = make_uint4(pkc(x[4 * i]), pkc(x[4 * i + 1]),
                                 pkc(x[4 * i + 2]), pkc(x[4 * i + 3]));
            *(uint4*)&ldsw[adr(i * 16 + (t >> 5), (t & 31) * 4)] = v;  // b128
        }
        BAR();                                                         // S1
        const int base = adr(t >> 2, t & 3);
#pragma unroll
        for (int r = 0; r < PER; ++r) x[r] = upkc(ldsw[base + r * 4]); // read2-merged
    }

    // ---- L1 bits {2..6} ----
    fwht_pk<16>(x);

    // XCHG2 (L1 -> L2): wave-local rows both sides -> NO barrier; packed words.
    {
        const int base = adr(t >> 2, t & 3);
#pragma unroll
        for (int r = 0; r < PER; ++r) ldsw[base + r * 4] = pkc(x[r]);  // write2-merged
        const int base2 = adr((t >> 6) * 16, ((t >> 2) & 15) * 4 + (t & 3));
#pragma unroll
        for (int r = 0; r < PER; ++r)
            x[r] = upkc(ldsw[base2 + (r & 15) * STRIDE + (r >> 4) * 64]);
    }

    // ---- L2 bits {7..10} (complex) ----
    fwht_pk<8>(x);

    // ---- rotation; output = REAL part only; 2^-14 folded into trig consts ----
    float tp = 0.f;
    if (t & 1)   tp += w[0];
    if (t & 2)   tp += w[1];
    if (t & 4)   tp += w[2];
    if (t & 8)   tp += w[3];
    if (t & 16)  tp += w[4];
    if (t & 32)  tp += w[5];
    if (t & 64)  tp += w[11];
    if (t & 128) tp += w[12];
    if (t & 256) tp += w[13];
    const float cd = __cosf(0.5f * w[7]);
    const float sd = __sinf(0.5f * w[7]);
    v2f q[16];
#pragma unroll
    for (int u = 0; u < 16; ++u) {
        float ph = tp;
        if (u & 1) ph += w[8];    // r&2
        if (u & 2) ph += w[9];    // r&4
        if (u & 4) ph += w[10];   // r&8
        if (u & 8) ph += w[6];    // r&16
        const float ang = -0.5f * ph;
        const float c0 = __cosf(ang) * SCALE;
        const float s0 = __sinf(ang) * SCALE;
        const float c1 = c0 * cd + s0 * sd;   // cos(ang - 0.5*w7), scaled
        const float s1 = s0 * cd - c0 * sd;   // sin(ang - 0.5*w7), scaled
        v2f xa = x[2 * u], xb = x[2 * u + 1];
        q[u][0] = xa[0] * c0 - xa[1] * s0;
        q[u][1] = xb[0] * c1 - xb[1] * s1;
    }

    // ---- transform 2 (reverse order, real fp32, packed): L2 bits {7..10} ----
    hbf(q);          // s7  (pair axis r0)
    fwht_q<4>(q);    // s8,s9,s10 (r1..r3)

    // XCHG3 (L2 -> L1): wave-local -> NO barrier.
    {
        const int base2 = adr((t >> 6) * 16, ((t >> 2) & 15) * 4 + (t & 3));
#pragma unroll
        for (int u = 0; u < 16; ++u) {
            lds[base2 + ((2 * u) & 15) * STRIDE + (u >> 3) * 64]     = q[u][0];
            lds[base2 + ((2 * u + 1) & 15) * STRIDE + (u >> 3) * 64] = q[u][1];
        }
        const int base = adr(t >> 2, t & 3);
#pragma unroll
        for (int u = 0; u < 16; ++u)
            q[u] = v2f{lds[base + 8 * u], lds[base + 8 * u + 4]};  // read2-merged
    }

    // ---- L1 bits {2..6} ----
    hbf(q);          // s2
    fwht_q<8>(q);    // s3..s6

    // XCHG4 (L1 -> L0): wave-local write, 1 barrier, cross-wave b128 reads.
    {
        const int base = adr(t >> 2, t & 3);
#pragma unroll
        for (int u = 0; u < 16; ++u) {
            lds[base + 8 * u]     = q[u][0];
            lds[base + 8 * u + 4] = q[u][1];
        }
        BAR();                                                         // S2
#pragma unroll
        for (int i = 0; i < 8; ++i) {
            float4 v = *(const float4*)&lds[adr(i * 16 + (t >> 5), (t & 31) * 4)];
            q[2 * i]     = v2f{v.x, v.y};
            q[2 * i + 1] = v2f{v.z, v.w};
        }
    }

    // ---- L0 bits {0,1,11,12,13} ----
    hbf(q);          // s0
    fwht_q<8>(q);    // s1, s11, s12, s13

    // ---- store real part, row-major, guarded, nontemporal ----
#pragma unroll
    for (int i = 0; i < 8; ++i) {
        const int s0 = i * 2048 + t * 4;
        if (ob + s0 + 3 < out_limit) {
            v4f vv = {q[2 * i][0], q[2 * i][1], q[2 * i + 1][0], q[2 * i + 1][1]};
            __builtin_nontemporal_store(vv, (v4f*)(o + s0));
        }
    }
}

__global__ void __launch_bounds__(THREADS, 2)
rx_kernel(const float* __restrict__ phr, const float* __restrict__ phim,
          const float* __restrict__ th, float* __restrict__ out,
          long long out_limit) {
    extern __shared__ float lds[];   // 67584 B; 1 block/CU (VGPR-capped anyway)
    uint32_t* ldsw = (uint32_t*)lds;
    const int b = blockIdx.x;
    const int t = threadIdx.x;
    const int rA = b, rB = b + GRID;

    v2f x[PER], y[PER];
    load_row(phr, phim, rA, t, x);   // row A: first in the VMEM queue
    load_row(phr, phim, rB, t, y);   // row B prefetch: in flight through all of A
    float wA[NQ];                    // w[k] multiplies bit k of s: w[k]=theta[13-k]
#pragma unroll
    for (int k = 0; k < NQ; ++k) wA[k] = th[rA * NQ + 13 - k];

    process_row(x, wA, lds, ldsw, t, out + (size_t)rA * STATE,
                (long long)rA * STATE, out_limit);

    float wB[NQ];                    // tiny, L2-hot; hidden under t1-B
#pragma unroll
    for (int k = 0; k < NQ; ++k) wB[k] = th[rB * NQ + 13 - k];

    BAR();   // every wave's XCHG4-A reads retired before B's XCHG1 overwrites LDS

    process_row(y, wB, lds, ldsw, t, out + (size_t)rB * STATE,
                (long long)rB * STATE, out_limit);
}

extern "C" void kernel_launch(void* const* d_in, const int* in_sizes, int n_in,
                              void* d_out, int out_size, void* d_ws, size_t ws_size,
                              hipStream_t stream) {
    const float* phr  = (const float*)d_in[0];
    const float* phim = (const float*)d_in[1];
    const float* th   = (const float*)d_in[2];
    float* out = (float*)d_out;
    // Dynamic LDS 67584 B > 64 KiB: raise the per-kernel dynamic-LDS cap.
    (void)hipFuncSetAttribute((const void*)rx_kernel,
                              hipFuncAttributeMaxDynamicSharedMemorySize,
                              LDS_WORDS * (int)sizeof(float));
    rx_kernel<<<GRID, THREADS, LDS_WORDS * sizeof(float), stream>>>(
        phr, phim, th, out, (long long)out_size);
}

// Round 5
// 106.785 us; speedup vs baseline: 1.0490x; 1.0490x over previous
//
#include <hip/hip_runtime.h>
#include <stdint.h>

#define NQ 14
#define STATE 16384
#define BATCH 512
#define THREADS 512
#define PER 32
#define STRIDE 132                 // 128 + 4-word pad: bank-rotates rows, keeps 16B align
#define LDS_WORDS (128 * STRIDE)  // 16896 words = 67584 B (dynamic LDS, 2 blocks/CU)
#define SCALE 6.103515625e-05f    // 2^-14: both FWHT norms folded into the rotation trig

typedef float v2f __attribute__((ext_vector_type(2)));  // (re, im) or (even, odd) pair
typedef float v4f __attribute__((ext_vector_type(4)));  // native vec4: nontemporal-capable

__device__ __forceinline__ int adr(int row, int col) { return row * STRIDE + col; }

// bf16-pair packing: one b32 word = complex element (re lo16, im hi16).
// Single v_cvt_pk_bf16_f32 (RNE) replaces the 4-op add/mask/shift sequence.
__device__ __forceinline__ uint32_t pkc(v2f v) {
    uint32_t w;
    asm("v_cvt_pk_bf16_f32 %0, %1, %2" : "=v"(w) : "v"(v[0]), "v"(v[1]));
    return w;
}
__device__ __forceinline__ v2f upkc(uint32_t w) {
    v2f v;
    v[0] = __uint_as_float(w << 16);
    v[1] = __uint_as_float(w & 0xFFFF0000u);
    return v;
}

// Packed complex FWHT over register bits m=1..MAXM (transform 1).
template <int MAXM>
__device__ __forceinline__ void fwht_pk(v2f (&x)[PER]) {
#pragma unroll
    for (int m = 1; m <= MAXM; m <<= 1) {
#pragma unroll
        for (int r = 0; r < PER; ++r) {
            if (!(r & m)) {
                v2f a = x[r], b = x[r | m];
                x[r] = a + b;
                x[r | m] = a - b;
            }
        }
    }
}
// Transform-2 helpers: 16 v2f regs hold 32 reals paired along LDS-adjacent bit r0.
// fwht_q: packed butterflies over the pair-INDEX bits (v_pk_add_f32).
template <int MAXM>
__device__ __forceinline__ void fwht_q(v2f (&x)[16]) {
#pragma unroll
    for (int m = 1; m <= MAXM; m <<= 1) {
#pragma unroll
        for (int u = 0; u < 16; ++u) {
            if (!(u & m)) {
                v2f a = x[u], c = x[u | m];
                x[u] = a + c;
                x[u | m] = a - c;
            }
        }
    }
}
// hbf: the horizontal butterfly over the pair axis itself (bit r0): (lo,hi)->(lo+hi,lo-hi).
__device__ __forceinline__ void hbf(v2f (&x)[16]) {
#pragma unroll
    for (int u = 0; u < 16; ++u) {
        float a = x[u][0], c = x[u][1];
        x[u][0] = a + c;
        x[u][1] = a - c;
    }
}

// Word-address maps (word index = complex element in t1, real f32 in t2):
// L0: s = (r>>2)*2048 + t*4 + (r&3)   reg bits s{0,1,11,12,13}; rows cross-wave
// L1: s = (t>>2)*128 + r*4 + (t&3)    reg bits s{2..6};  rows [16w,16w+16): wave-local
// L2: s = (t>>6)*2048 + (r&15)*128 + (r>>4)*64 + ((t>>2)&15)*4 + (t&3)
//     reg bits s{6..10}; rows [16w,16w+16): wave-local
// LDS address of s: adr(s>>7, s&127).  All patterns <=2 lanes/bank (free).
// t2 pair axis = r0: partners are {+4B (L1/L0), +STRIDE*4B (L2)} apart -> identical
// ds_read2/write2 merging as the old scalar code, only the REGISTER form changes.

__global__ void __launch_bounds__(THREADS, 4)
rx_kernel(const float* __restrict__ phr, const float* __restrict__ phim,
          const float* __restrict__ th, float* __restrict__ out,
          long long out_limit) {
    extern __shared__ float lds[];   // 67584 B -> 2 blocks/CU (135 KiB of 160)
    uint32_t* ldsw = (uint32_t*)lds;
    const int b = blockIdx.x;
    const int t = threadIdx.x;
    v2f x[PER];

    const float* pr = phr + (size_t)b * STATE;
    const float* pi = phim + (size_t)b * STATE;
#pragma unroll
    for (int i = 0; i < 8; ++i) {
        float4 a = *(const float4*)(pr + i * 2048 + t * 4);
        float4 c = *(const float4*)(pi + i * 2048 + t * 4);
        x[4 * i]     = v2f{a.x, c.x};
        x[4 * i + 1] = v2f{a.y, c.y};
        x[4 * i + 2] = v2f{a.z, c.z};
        x[4 * i + 3] = v2f{a.w, c.w};
    }
    float w[NQ];   // w[k] multiplies bit k (LSB) of s: w[k] = theta[13-k]
#pragma unroll
    for (int k = 0; k < NQ; ++k) w[k] = th[b * NQ + 13 - k];

    // ---- transform 1: L0 bits {0,1,11,12,13} (complex fp32, packed math) ----
    fwht_pk<16>(x);

    // XCHG1 (L0 -> L1): ONE pass, complex packed as bf16-pair words. 1 barrier.
    {
#pragma unroll
        for (int i = 0; i < 8; ++i) {
            uint4 v = make_uint4(pkc(x[4 * i]), pkc(x[4 * i + 1]),
                                 pkc(x[4 * i + 2]), pkc(x[4 * i + 3]));
            *(uint4*)&ldsw[adr(i * 16 + (t >> 5), (t & 31) * 4)] = v;  // b128
        }
        __syncthreads();                                               // S1
        const int base = adr(t >> 2, t & 3);
#pragma unroll
        for (int r = 0; r < PER; ++r) x[r] = upkc(ldsw[base + r * 4]); // read2-merged
    }

    // ---- L1 bits {2..6} ----
    fwht_pk<16>(x);

    // XCHG2 (L1 -> L2): wave-local rows both sides -> NO barrier; packed words.
    {
        const int base = adr(t >> 2, t & 3);
#pragma unroll
        for (int r = 0; r < PER; ++r) ldsw[base + r * 4] = pkc(x[r]);  // write2-merged
        const int base2 = adr((t >> 6) * 16, ((t >> 2) & 15) * 4 + (t & 3));
#pragma unroll
        for (int r = 0; r < PER; ++r)
            x[r] = upkc(ldsw[base2 + (r & 15) * STRIDE + (r >> 4) * 64]);
    }

    // ---- L2 bits {7..10} (complex) ----
    fwht_pk<8>(x);

    // ---- rotation; output = REAL part only; 2^-14 folded into trig consts ----
    // q[u] = (real(rot(r=2u)), real(rot(r=2u+1))): t2 state, paired along r0.
    // Partner angle differs by -0.5*w[7]: angle-addition halves the sincos count.
    float tp = 0.f;
    if (t & 1)   tp += w[0];
    if (t & 2)   tp += w[1];
    if (t & 4)   tp += w[2];
    if (t & 8)   tp += w[3];
    if (t & 16)  tp += w[4];
    if (t & 32)  tp += w[5];
    if (t & 64)  tp += w[11];
    if (t & 128) tp += w[12];
    if (t & 256) tp += w[13];
    const float cd = __cosf(0.5f * w[7]);
    const float sd = __sinf(0.5f * w[7]);
    v2f q[16];
#pragma unroll
    for (int u = 0; u < 16; ++u) {
        float ph = tp;
        if (u & 1) ph += w[8];    // r&2
        if (u & 2) ph += w[9];    // r&4
        if (u & 4) ph += w[10];   // r&8
        if (u & 8) ph += w[6];    // r&16
        const float ang = -0.5f * ph;
        const float c0 = __cosf(ang) * SCALE;
        const float s0 = __sinf(ang) * SCALE;
        const float c1 = c0 * cd + s0 * sd;   // cos(ang - 0.5*w7), scaled
        const float s1 = s0 * cd - c0 * sd;   // sin(ang - 0.5*w7), scaled
        v2f xa = x[2 * u], xb = x[2 * u + 1];
        q[u][0] = xa[0] * c0 - xa[1] * s0;
        q[u][1] = xb[0] * c1 - xb[1] * s1;
    }

    // ---- transform 2 (reverse order, real fp32, packed): L2 bits {7..10} ----
    hbf(q);          // s7  (pair axis r0)
    fwht_q<4>(q);    // s8,s9,s10 (r1..r3); r4/s6 untouched here (done in L1)

    // XCHG3 (L2 -> L1): wave-local -> NO barrier; same addresses as before.
    {
        const int base2 = adr((t >> 6) * 16, ((t >> 2) & 15) * 4 + (t & 3));
#pragma unroll
        for (int u = 0; u < 16; ++u) {
            lds[base2 + ((2 * u) & 15) * STRIDE + (u >> 3) * 64]     = q[u][0];
            lds[base2 + ((2 * u + 1) & 15) * STRIDE + (u >> 3) * 64] = q[u][1];
        }
        const int base = adr(t >> 2, t & 3);
#pragma unroll
        for (int u = 0; u < 16; ++u)
            q[u] = v2f{lds[base + 8 * u], lds[base + 8 * u + 4]};  // read2-merged
    }

    // ---- L1 bits {2..6} ----
    hbf(q);          // s2  (pair axis r'0)
    fwht_q<8>(q);    // s3..s6 (r'1..r'4)

    // XCHG4 (L1 -> L0): wave-local write, 1 barrier, cross-wave b128 reads.
    {
        const int base = adr(t >> 2, t & 3);
#pragma unroll
        for (int u = 0; u < 16; ++u) {
            lds[base + 8 * u]     = q[u][0];
            lds[base + 8 * u + 4] = q[u][1];
        }
        __syncthreads();                                               // S2
#pragma unroll
        for (int i = 0; i < 8; ++i) {
            float4 v = *(const float4*)&lds[adr(i * 16 + (t >> 5), (t & 31) * 4)];
            q[2 * i]     = v2f{v.x, v.y};   // pairs (4i,4i+1),(4i+2,4i+3): intra-float4
            q[2 * i + 1] = v2f{v.z, v.w};
        }
    }

    // ---- L0 bits {0,1,11,12,13} ----
    hbf(q);          // s0  (pair axis r0)
    fwht_q<8>(q);    // s1 (r1), s11 (r2), s12 (r3), s13 (r4)

    // ---- store real part, (512,16384) row-major, guarded, nontemporal ----
    float* o = out + (size_t)b * STATE;
    const long long ob = (long long)b * STATE;
#pragma unroll
    for (int i = 0; i < 8; ++i) {
        const int s0 = i * 2048 + t * 4;
        if (ob + s0 + 3 < out_limit) {
            v4f vv = {q[2 * i][0], q[2 * i][1], q[2 * i + 1][0], q[2 * i + 1][1]};
            __builtin_nontemporal_store(vv, (v4f*)(o + s0));
        }
    }
}

extern "C" void kernel_launch(void* const* d_in, const int* in_sizes, int n_in,
                              void* d_out, int out_size, void* d_ws, size_t ws_size,
                              hipStream_t stream) {
    const float* phr  = (const float*)d_in[0];
    const float* phim = (const float*)d_in[1];
    const float* th   = (const float*)d_in[2];
    float* out = (float*)d_out;
    // Dynamic LDS 67584 B > 64 KiB: raise the per-kernel dynamic-LDS cap.
    (void)hipFuncSetAttribute((const void*)rx_kernel,
                              hipFuncAttributeMaxDynamicSharedMemorySize,
                              LDS_WORDS * (int)sizeof(float));
    rx_kernel<<<BATCH, THREADS, LDS_WORDS * sizeof(float), stream>>>(
        phr, phim, th, out, (long long)out_size);
}